// Round 3
// baseline (20.330 us; speedup 1.0000x reference)
//
#include <hip/hip_runtime.h>
#include <math.h>

#define CI 16
#define CO 32
#define HH 64
#define WW 64
#define KK 3
#define TH 4
#define TW 16
#define HALO_H (TH + 2)
#define HALO_W (TW + 2)
#define NTAP 9

// RingConv2d: out[b,co,ho,wo] = atan2( sum sin(x_p - w), sum cos(x_p - w) )
// over (ci,kh,kw), zero-padded x. Padded positions contribute (cos,sin)=(1,0).
// dir_x = conv(cos x, cos w) + conv(sin x, sin w)
// dir_y = conv(sin x, cos w) - conv(cos x, sin w)
//
// R3 structure: weights precomputed to d_ws as (wc0,ws0,wc1,ws1) per
// (co-pair, ci, tap). Main loop batches ALL loads of a ci-slice (9 uniform
// s_load float4 + 9 lane-varying ds_read_b64) BEFORE the 72 FMAs, so the
// mixed lgkmcnt drain happens once per 144 VALU cycles, not per tap
// (SMEM and DS share lgkmcnt and return out-of-order -> per-tap waits
// were full drains: the R1/R2 bottleneck).

__global__ __launch_bounds__(256)
void ringconv_wprep(const float* __restrict__ w, float* __restrict__ wtab) {
    int i = blockIdx.x * 256 + threadIdx.x;
    if (i >= CI * CO * NTAP) return;
    int ci  = i / (CO * NTAP);
    int rem = i - ci * (CO * NTAP);
    int co  = rem / NTAP;
    int tap = rem - co * NTAP;
    float s, c;
    __sincosf(w[i], &s, &c);
    int cg = co >> 1, col = co & 1;
    float* dst = wtab + (((cg * CI + ci) * NTAP + tap) << 2) + (col << 1);
    dst[0] = c;
    dst[1] = s;
}

__global__ __launch_bounds__(1024)
void ringconv_main(const float* __restrict__ x,
                   const float* __restrict__ wtab,
                   float* __restrict__ out) {
    // (cos x, sin x) input tile with halo: 16*6*18 float2 = 13824 B
    __shared__ float2 xs[CI][HALO_H][HALO_W];

    const int tid = threadIdx.x;
    const int b   = blockIdx.z;
    const int th0 = blockIdx.y * TH;
    const int tw0 = blockIdx.x * TW;

    // --- stage input tile sincos; out-of-bounds (zero-pad) -> (1,0) ---
    for (int i = tid; i < CI * HALO_H * HALO_W; i += 1024) {
        int ci  = i / (HALO_H * HALO_W);
        int rem = i - ci * (HALO_H * HALO_W);
        int rr  = rem / HALO_W;
        int cc  = rem - rr * HALO_W;
        int h  = th0 + rr - 1;
        int ww = tw0 + cc - 1;
        float xv = 0.0f;
        if (h >= 0 && h < HH && ww >= 0 && ww < WW)
            xv = x[((b * CI + ci) * HH + h) * WW + ww];
        float s, c2;
        __sincosf(xv, &s, &c2);          // xv==0 -> (1,0): correct pad value
        xs[ci][rr][cc] = make_float2(c2, s);
    }
    __syncthreads();

    const int lane = tid & 63;
    const int wid  = tid >> 6;                             // 0..15 co-pair group
    const int cg   = __builtin_amdgcn_readfirstlane(wid);  // force SGPR-uniform
    const int r    = lane >> 4;                            // 0..3  spatial row
    const int c    = lane & 15;                            // 0..15 spatial col

    const float4* __restrict__ wt =
        (const float4*)wtab + cg * (CI * NTAP);            // 9 float4 per ci

    float ax0 = 0.f, ay0 = 0.f, ax1 = 0.f, ay1 = 0.f;

    #pragma unroll 4
    for (int ci = 0; ci < CI; ++ci) {
        // ---- batched weight loads (wave-uniform address -> s_load) ----
        float4 wv[NTAP];
        #pragma unroll
        for (int t = 0; t < NTAP; ++t)
            wv[t] = wt[ci * NTAP + t];

        // ---- batched input loads (lane-varying ds_read_b64) ----
        float2 p[KK][KK];
        #pragma unroll
        for (int kh = 0; kh < KK; ++kh)
            #pragma unroll
            for (int kw = 0; kw < KK; ++kw)
                p[kh][kw] = xs[ci][r + kh][c + kw];

        // ---- 72 FMAs, all operands in registers ----
        #pragma unroll
        for (int kh = 0; kh < KK; ++kh) {
            #pragma unroll
            for (int kw = 0; kw < KK; ++kw) {
                const float2 pp = p[kh][kw];
                const float4 w4 = wv[kh * KK + kw];
                ax0 = fmaf(pp.x, w4.x, fmaf(pp.y,  w4.y, ax0));
                ay0 = fmaf(pp.y, w4.x, fmaf(pp.x, -w4.y, ay0));
                ax1 = fmaf(pp.x, w4.z, fmaf(pp.y,  w4.w, ax1));
                ay1 = fmaf(pp.y, w4.z, fmaf(pp.x, -w4.w, ay1));
            }
        }
    }

    const int co0  = cg * 2;
    const int oidx = ((b * CO + co0) * HH + (th0 + r)) * WW + (tw0 + c);
    out[oidx]           = atan2f(ay0, ax0);
    out[oidx + HH * WW] = atan2f(ay1, ax1);
}

extern "C" void kernel_launch(void* const* d_in, const int* in_sizes, int n_in,
                              void* d_out, int out_size, void* d_ws, size_t ws_size,
                              hipStream_t stream) {
    const float* x = (const float*)d_in[0];   // (B, 16, 64, 64) fp32
    const float* w = (const float*)d_in[1];   // (1, 16, 32, 1, 1, 3, 3) fp32
    float* out  = (float*)d_out;              // (B, 32, 64, 64) fp32
    float* wtab = (float*)d_ws;               // 16*16*9*4 floats = 36 KB

    const int B = in_sizes[0] / (CI * HH * WW);

    ringconv_wprep<<<(CI * CO * NTAP + 255) / 256, 256, 0, stream>>>(w, wtab);

    dim3 grid(WW / TW, HH / TH, B);           // 4 x 16 x 4 = 256 blocks
    ringconv_main<<<grid, 1024, 0, stream>>>(x, wtab, out);
}